// Round 2
// baseline (301.082 us; speedup 1.0000x reference)
//
#include <hip/hip_runtime.h>
#include <hip/hip_bf16.h>
#include <math.h>

// KNRM fused kernel for MI355X (gfx950) — round 2.
// B=256, Q=32, D=512, E=300, V=100k, K=11.
//
// R2 structure: no doc LDS staging. Doc rows load straight into MFMA B-operand
// registers (B[n=lane&15][k=quad*8+j]); norms via cross-quad shuffles; zero
// barriers in the doc loop. Docs split 4x across blocks (grid 1024) for
// occupancy; per-block partial qk written to d_ws; tiny epilogue kernel.
// Kernel 0 (sigma=1e-4) = exact-token-match counter via integer compare.

#define NB 256
#define NQ 32
#define ND 512
#define NE 300
#define LROW 328    // qlds row stride in bf16 (656 B; 4-bank row offset -> 2-way=free)
#define SPLITS 4
#define DPB 128     // docs per block
#define NT 256
#define NK 11
#define QK_SZ (NQ * NK)   // 352

typedef __bf16 bf16x8 __attribute__((ext_vector_type(8)));
typedef __bf16 bf16x4 __attribute__((ext_vector_type(4)));
typedef float f32x4 __attribute__((ext_vector_type(4)));

__global__ __launch_bounds__(NT, 3) void knrm_main(
    const int* __restrict__ qtok,
    const int* __restrict__ dtok,
    const float* __restrict__ emb,
    float* __restrict__ partial)   // [NB][SPLITS][QK_SZ]
{
  __shared__ __align__(16) __bf16 qlds[NQ][LROW];
  __shared__ float qscale[NQ];
  __shared__ float qkl[QK_SZ];

  const int b    = blockIdx.x >> 2;
  const int sp   = blockIdx.x & 3;
  const int t    = threadIdx.x;
  const int lane = t & 63;
  const int w    = t >> 6;
  const int quad = lane >> 4;
  const int l15  = lane & 15;

  // init qkl for k>=1 (k==0 plain-stored by match counter)
  for (int i = t; i < QK_SZ; i += NT)
    if (i % NK) qkl[i] = 0.0f;

  // ---- query gather + norm + kernel-0 exact-match counts ----
  {
    const int r = t >> 3;      // query row 0..31, 8 threads/row (same wave)
    const int j = t & 7;
    const int tq = qtok[b * NQ + r];
    const float4* rowp = (const float4*)(emb + (size_t)tq * NE);
    float ss = 0.0f;
    for (int c = j; c < 75; c += 8) {
      float4 v = rowp[c];
      ss += v.x * v.x + v.y * v.y + v.z * v.z + v.w * v.w;
      bf16x4 h;
      h[0] = (__bf16)v.x; h[1] = (__bf16)v.y; h[2] = (__bf16)v.z; h[3] = (__bf16)v.w;
      *(bf16x4*)&qlds[r][4 * c] = h;
    }
    if (j < 5) { bf16x4 z = {}; *(bf16x4*)&qlds[r][NE + 4 * j] = z; }  // K-pad 300..319
    ss += __shfl_xor(ss, 1, 8);
    ss += __shfl_xor(ss, 2, 8);
    ss += __shfl_xor(ss, 4, 8);
    if (j == 0) qscale[r] = (tq > 0) ? 1.0f / (sqrtf(ss) + 1e-13f) : 0.0f;

    // kernel 0: count of this block's docs with identical (nonzero) token
    int cnt = 0;
    #pragma unroll 4
    for (int i = 0; i < 16; ++i) {
      int td = dtok[b * ND + sp * DPB + j + 8 * i];
      cnt += (tq > 0 && td == tq) ? 1 : 0;
    }
    cnt += __shfl_xor(cnt, 1, 8);
    cnt += __shfl_xor(cnt, 2, 8);
    cnt += __shfl_xor(cnt, 4, 8);
    if (j == 0) qkl[r * NK] = (float)cnt;
  }
  __syncthreads();

  const float muk[10] = {0.9f, 0.7f, 0.5f, 0.3f, 0.1f,
                         -0.1f, -0.3f, -0.5f, -0.7f, -0.9f};

  float rbf[2][4][10] = {};   // [mtile][reg][kernel] accumulators

  // ---- doc loop: wave w handles 16-doc groups w and w+4; no barriers ----
  #pragma unroll 1
  for (int gi = 0; gi < 2; ++gi) {
    const int g = w + 4 * gi;
    const int d = sp * DPB + g * 16 + l15;          // this lane's doc row (n = l15)
    const int td = dtok[b * ND + d];
    const float* rowf = emb + (size_t)td * NE;

    // Load B fragments: lane holds B[n=l15][k=quad*8+j] for each 32-K step.
    // Per K-step the 4 lanes sharing a row read 128 B contiguous.
    float ss = 0.0f;
    bf16x8 bfrag[10];
    #pragma unroll
    for (int kk = 0; kk < 9; ++kk) {
      const float4* p = (const float4*)(rowf + kk * 32 + quad * 8);
      float4 v0 = p[0];
      float4 v1 = p[1];
      ss += v0.x * v0.x + v0.y * v0.y + v0.z * v0.z + v0.w * v0.w;
      ss += v1.x * v1.x + v1.y * v1.y + v1.z * v1.z + v1.w * v1.w;
      bf16x8 h;
      h[0] = (__bf16)v0.x; h[1] = (__bf16)v0.y; h[2] = (__bf16)v0.z; h[3] = (__bf16)v0.w;
      h[4] = (__bf16)v1.x; h[5] = (__bf16)v1.y; h[6] = (__bf16)v1.z; h[7] = (__bf16)v1.w;
      bfrag[kk] = h;
    }
    {  // kk = 9: elements 288+quad*8+j, guard e < 300 (K-pad to 320)
      const int base = 288 + quad * 8;
      bf16x8 h;
      #pragma unroll
      for (int j = 0; j < 8; ++j) {
        const int e = base + j;
        float v = (e < NE) ? rowf[e] : 0.0f;
        ss += v * v;
        h[j] = (__bf16)v;
      }
      bfrag[9] = h;
    }
    ss += __shfl_xor(ss, 16);
    ss += __shfl_xor(ss, 32);
    const float dsc = (td > 0) ? 1.0f / (sqrtf(ss) + 1e-13f) : 0.0f;

    // Two 16x16 m-tiles cover all 32 query rows; A from LDS, B from regs.
    #pragma unroll
    for (int mt = 0; mt < 2; ++mt) {
      f32x4 acc = {};
      #pragma unroll
      for (int kk = 0; kk < 10; ++kk) {
        bf16x8 av = *(const bf16x8*)&qlds[mt * 16 + l15][kk * 32 + quad * 8];
        acc = __builtin_amdgcn_mfma_f32_16x16x32_bf16(av, bfrag[kk], acc, 0, 0, 0);
      }
      // C layout: col(doc)=l15, row(q)=quad*4+reg
      #pragma unroll
      for (int r = 0; r < 4; ++r) {
        const float qs = qscale[mt * 16 + quad * 4 + r];
        const float s = qs * dsc;
        const float mm = (s == 0.0f) ? 1e8f : acc[r] * s;   // masked -> rbf underflows to 0
        #pragma unroll
        for (int k = 0; k < 10; ++k) {
          float dd = mm - muk[k];
          rbf[mt][r][k] += __builtin_amdgcn_exp2f(dd * dd * -72.13475204444817f);
        }
      }
    }
  }

  // ---- reduce over the 16 doc-lanes, combine into block qk ----
  #pragma unroll
  for (int mt = 0; mt < 2; ++mt)
    #pragma unroll
    for (int r = 0; r < 4; ++r)
      #pragma unroll
      for (int k = 0; k < 10; ++k) {
        float v = rbf[mt][r][k];
        v += __shfl_xor(v, 1);
        v += __shfl_xor(v, 2);
        v += __shfl_xor(v, 4);
        v += __shfl_xor(v, 8);
        if (l15 == 0)
          atomicAdd(&qkl[(mt * 16 + quad * 4 + r) * NK + k + 1], v);
      }
  __syncthreads();

  // ---- write this block's partial qk slice ----
  float* pp = partial + ((size_t)b * SPLITS + sp) * QK_SZ;
  for (int i = t; i < QK_SZ; i += NT) pp[i] = qkl[i];
}

__global__ __launch_bounds__(64) void knrm_epi(
    const float* __restrict__ partial,
    const float* __restrict__ fcw,
    const float* __restrict__ fcb,
    float* __restrict__ out)
{
  const int b = blockIdx.x;
  const int lane = threadIdx.x;
  const float* pb = partial + (size_t)b * SPLITS * QK_SZ;
  float acc = 0.0f;
  for (int i = lane; i < QK_SZ; i += 64) {
    float s = pb[i] + pb[i + QK_SZ] + pb[i + 2 * QK_SZ] + pb[i + 3 * QK_SZ];
    int k = i % NK;
    acc += logf(fmaxf(s, 1e-10f)) * 0.01f * fcw[k];
  }
  #pragma unroll
  for (int off = 1; off < 64; off <<= 1) acc += __shfl_xor(acc, off);
  if (lane == 0) out[b] = acc + fcb[0];
}

extern "C" void kernel_launch(void* const* d_in, const int* in_sizes, int n_in,
                              void* d_out, int out_size, void* d_ws, size_t ws_size,
                              hipStream_t stream) {
  const int* qtok = (const int*)d_in[0];
  const int* dtok = (const int*)d_in[1];
  const float* emb = (const float*)d_in[2];
  const float* fcw = (const float*)d_in[3];
  const float* fcb = (const float*)d_in[4];
  float* out = (float*)d_out;
  float* partial = (float*)d_ws;   // NB*SPLITS*QK_SZ floats = 1.44 MB

  knrm_main<<<NB * SPLITS, NT, 0, stream>>>(qtok, dtok, emb, partial);
  knrm_epi<<<NB, 64, 0, stream>>>(partial, fcw, fcb, out);
}

// Round 3
// 294.101 us; speedup vs baseline: 1.0237x; 1.0237x over previous
//
#include <hip/hip_runtime.h>
#include <hip/hip_bf16.h>
#include <math.h>

// KNRM fused kernel for MI355X (gfx950) — round 3.
// B=256, Q=32, D=512, E=300, V=100k, K=11.
//
// R3: R2's barrier-free doc loop (B-fragments straight from global into MFMA
// registers) but ONE m-tile per wave (40-reg rbf accumulators, not 80) and
// amdgpu_waves_per_eu(4,4) to pin the allocator at VGPR<=128 — R2's 84-VGPR
// squeeze spilled 155 MB of scratch to HBM.
// Kernel 0 (sigma=1e-4) = exact-token-match counter via integer compare.

#define NB 256
#define NQ 32
#define ND 512
#define NE 300
#define LROW 328    // qlds row stride in bf16 (656 B); quarter-wave b128 reads -> 2-way = free
#define SPLITS 4
#define DPB 128     // docs per block
#define NT 512
#define NK 11
#define QK_SZ (NQ * NK)   // 352

typedef __bf16 bf16x8 __attribute__((ext_vector_type(8)));
typedef __bf16 bf16x4 __attribute__((ext_vector_type(4)));
typedef float f32x4 __attribute__((ext_vector_type(4)));

__global__ __launch_bounds__(NT) __attribute__((amdgpu_waves_per_eu(4, 4)))
void knrm_main(
    const int* __restrict__ qtok,
    const int* __restrict__ dtok,
    const float* __restrict__ emb,
    float* __restrict__ partial)   // [NB][SPLITS][QK_SZ]
{
  __shared__ __align__(16) __bf16 qlds[NQ][LROW];
  __shared__ float qscale[NQ];
  __shared__ float qkl[QK_SZ];

  const int b    = blockIdx.x >> 2;
  const int sp   = blockIdx.x & 3;
  const int t    = threadIdx.x;
  const int lane = t & 63;
  const int w    = t >> 6;
  const int quad = lane >> 4;
  const int l15  = lane & 15;

  // init qkl for k>=1 (k==0 plain-stored by match counter)
  for (int i = t; i < QK_SZ; i += NT)
    if (i % NK) qkl[i] = 0.0f;

  // ---- query gather + norm + kernel-0 exact-match counts ----
  {
    const int r = t >> 4;      // query row 0..31, 16 threads/row (same wave)
    const int j = t & 15;
    const int tq = qtok[b * NQ + r];
    const float4* rowp = (const float4*)(emb + (size_t)tq * NE);
    float ss = 0.0f;
    for (int c = j; c < 75; c += 16) {
      float4 v = rowp[c];
      ss += v.x * v.x + v.y * v.y + v.z * v.z + v.w * v.w;
      bf16x4 h;
      h[0] = (__bf16)v.x; h[1] = (__bf16)v.y; h[2] = (__bf16)v.z; h[3] = (__bf16)v.w;
      *(bf16x4*)&qlds[r][4 * c] = h;
    }
    if (j < 5) { bf16x4 z = {}; *(bf16x4*)&qlds[r][NE + 4 * j] = z; }  // K-pad 300..319
    ss += __shfl_xor(ss, 1, 16);
    ss += __shfl_xor(ss, 2, 16);
    ss += __shfl_xor(ss, 4, 16);
    ss += __shfl_xor(ss, 8, 16);
    if (j == 0) qscale[r] = (tq > 0) ? 1.0f / (sqrtf(ss) + 1e-13f) : 0.0f;

    // kernel 0: count of this block's 128 docs with identical (nonzero) token
    int cnt = 0;
    #pragma unroll
    for (int i = 0; i < 8; ++i) {
      int td = dtok[b * ND + sp * DPB + j + 16 * i];
      cnt += (tq > 0 && td == tq) ? 1 : 0;
    }
    cnt += __shfl_xor(cnt, 1, 16);
    cnt += __shfl_xor(cnt, 2, 16);
    cnt += __shfl_xor(cnt, 4, 16);
    cnt += __shfl_xor(cnt, 8, 16);
    if (j == 0) qkl[r * NK] = (float)cnt;
  }
  __syncthreads();

  const int mt = w >> 2;     // this wave's m-tile (q rows 16mt..16mt+15)
  const int g0 = w & 3;      // this wave's doc-group within a 64-doc pass

  float qs[4];
  #pragma unroll
  for (int r = 0; r < 4; ++r) qs[r] = qscale[mt * 16 + quad * 4 + r];

  const float muk[10] = {0.9f, 0.7f, 0.5f, 0.3f, 0.1f,
                         -0.1f, -0.3f, -0.5f, -0.7f, -0.9f};
  float rbf[4][10] = {};   // [reg][kernel] accumulators — 40 VGPRs

  // ---- doc loop: 2 passes x 16 docs per wave; no barriers ----
  #pragma unroll 1
  for (int pass = 0; pass < 2; ++pass) {
    const int td = dtok[b * ND + sp * DPB + pass * 64 + g0 * 16 + l15];
    const float* rowf = emb + (size_t)td * NE;

    // B fragments: lane holds B[n=l15][k=quad*8+j]; 4 lanes/row read 128 B contiguous per K-step.
    float ss = 0.0f;
    bf16x8 bfrag[10];
    #pragma unroll
    for (int kk = 0; kk < 9; ++kk) {
      const float4* p = (const float4*)(rowf + kk * 32 + quad * 8);
      float4 v0 = p[0];
      float4 v1 = p[1];
      ss += v0.x * v0.x + v0.y * v0.y + v0.z * v0.z + v0.w * v0.w;
      ss += v1.x * v1.x + v1.y * v1.y + v1.z * v1.z + v1.w * v1.w;
      bf16x8 h;
      h[0] = (__bf16)v0.x; h[1] = (__bf16)v0.y; h[2] = (__bf16)v0.z; h[3] = (__bf16)v0.w;
      h[4] = (__bf16)v1.x; h[5] = (__bf16)v1.y; h[6] = (__bf16)v1.z; h[7] = (__bf16)v1.w;
      bfrag[kk] = h;
    }
    {  // kk=9: elements 288..299 valid, 300..319 zero-pad
      bf16x8 h = {};
      if (quad == 0) {
        float4 v0 = *(const float4*)(rowf + 288);
        float4 v1 = *(const float4*)(rowf + 292);
        ss += v0.x * v0.x + v0.y * v0.y + v0.z * v0.z + v0.w * v0.w;
        ss += v1.x * v1.x + v1.y * v1.y + v1.z * v1.z + v1.w * v1.w;
        h[0] = (__bf16)v0.x; h[1] = (__bf16)v0.y; h[2] = (__bf16)v0.z; h[3] = (__bf16)v0.w;
        h[4] = (__bf16)v1.x; h[5] = (__bf16)v1.y; h[6] = (__bf16)v1.z; h[7] = (__bf16)v1.w;
      } else if (quad == 1) {
        float4 v0 = *(const float4*)(rowf + 296);
        ss += v0.x * v0.x + v0.y * v0.y + v0.z * v0.z + v0.w * v0.w;
        h[0] = (__bf16)v0.x; h[1] = (__bf16)v0.y; h[2] = (__bf16)v0.z; h[3] = (__bf16)v0.w;
      }
      bfrag[9] = h;
    }
    ss += __shfl_xor(ss, 16);
    ss += __shfl_xor(ss, 32);
    const float dsc = (td > 0) ? 1.0f / (sqrtf(ss) + 1e-13f) : 0.0f;

    // MFMA: this wave's 16x16 tile, K=320
    f32x4 acc = {};
    #pragma unroll
    for (int kk = 0; kk < 10; ++kk) {
      bf16x8 av = *(const bf16x8*)&qlds[mt * 16 + l15][kk * 32 + quad * 8];
      acc = __builtin_amdgcn_mfma_f32_16x16x32_bf16(av, bfrag[kk], acc, 0, 0, 0);
    }

    // RBF accumulate (kernels 1..10). C layout: col(doc)=l15, row(q)=quad*4+reg.
    #pragma unroll
    for (int r = 0; r < 4; ++r) {
      const float s = qs[r] * dsc;
      const float mm = (s == 0.0f) ? 1e8f : acc[r] * s;   // masked -> all rbf underflow to 0
      #pragma unroll
      for (int k = 0; k < 10; ++k) {
        float dd = mm - muk[k];
        rbf[r][k] += __builtin_amdgcn_exp2f(dd * dd * -72.13475204444817f);
      }
    }
  }

  // ---- reduce over the 16 doc-lanes, combine into block qk ----
  #pragma unroll
  for (int r = 0; r < 4; ++r)
    #pragma unroll
    for (int k = 0; k < 10; ++k) {
      float v = rbf[r][k];
      v += __shfl_xor(v, 1);
      v += __shfl_xor(v, 2);
      v += __shfl_xor(v, 4);
      v += __shfl_xor(v, 8);
      if (l15 == 0)
        atomicAdd(&qkl[(mt * 16 + quad * 4 + r) * NK + k + 1], v);
    }
  __syncthreads();

  // ---- write this block's partial qk slice ----
  float* pp = partial + ((size_t)b * SPLITS + sp) * QK_SZ;
  for (int i = t; i < QK_SZ; i += NT) pp[i] = qkl[i];
}

__global__ __launch_bounds__(64) void knrm_epi(
    const float* __restrict__ partial,
    const float* __restrict__ fcw,
    const float* __restrict__ fcb,
    float* __restrict__ out)
{
  const int b = blockIdx.x;
  const int lane = threadIdx.x;
  const float* pb = partial + (size_t)b * SPLITS * QK_SZ;
  float acc = 0.0f;
  for (int i = lane; i < QK_SZ; i += 64) {
    float s = pb[i] + pb[i + QK_SZ] + pb[i + 2 * QK_SZ] + pb[i + 3 * QK_SZ];
    int k = i % NK;
    acc += logf(fmaxf(s, 1e-10f)) * 0.01f * fcw[k];
  }
  #pragma unroll
  for (int off = 1; off < 64; off <<= 1) acc += __shfl_xor(acc, off);
  if (lane == 0) out[b] = acc + fcb[0];
}

extern "C" void kernel_launch(void* const* d_in, const int* in_sizes, int n_in,
                              void* d_out, int out_size, void* d_ws, size_t ws_size,
                              hipStream_t stream) {
  const int* qtok = (const int*)d_in[0];
  const int* dtok = (const int*)d_in[1];
  const float* emb = (const float*)d_in[2];
  const float* fcw = (const float*)d_in[3];
  const float* fcb = (const float*)d_in[4];
  float* out = (float*)d_out;
  float* partial = (float*)d_ws;   // NB*SPLITS*QK_SZ floats = 1.44 MB

  knrm_main<<<NB * SPLITS, NT, 0, stream>>>(qtok, dtok, emb, partial);
  knrm_epi<<<NB, 64, 0, stream>>>(partial, fcw, fcb, out);
}

// Round 4
// 206.883 us; speedup vs baseline: 1.4553x; 1.4216x over previous
//
#include <hip/hip_runtime.h>
#include <hip/hip_bf16.h>
#include <math.h>

// KNRM fused kernel for MI355X (gfx950) — round 4.
// B=256, Q=32, D=512, E=300, V=100k, K=11.
//
// R4 = R1's spill-free LDS-staged structure (VGPR 52) + 2 blocks/CU residency:
// docs split 2x across blocks (grid 512), so two blocks per CU interleave their
// gather-barrier phases. R2/R3's register-resident B-fragments spilled 150 MB
// to scratch (compiler pins VGPR<=84 for occupancy) — abandoned.
// Kernel 0 (sigma=1e-4) = exact-token-match counter via integer compare.

#define NB 256
#define NQ 32
#define ND 512
#define NE 300
#define NF4 75      // float4 per emb row
#define LROW 328    // LDS row stride in bf16 (656 B = 16B-aligned, 4-bank row offset)
#define SPLITS 2
#define DPB 256     // docs per block
#define CHUNK 64
#define NCHUNK 4
#define NT 512
#define NK 11
#define QK_SZ (NQ * NK)   // 352

typedef __bf16 bf16x8 __attribute__((ext_vector_type(8)));
typedef __bf16 bf16x4 __attribute__((ext_vector_type(4)));
typedef float f32x4 __attribute__((ext_vector_type(4)));

__global__ __launch_bounds__(NT, 1) void knrm_main(
    const int* __restrict__ qtok,
    const int* __restrict__ dtok,
    const float* __restrict__ emb,
    float* __restrict__ partial)   // [NB][SPLITS][QK_SZ]
{
  __shared__ __align__(16) __bf16 qlds[NQ][LROW];
  __shared__ __align__(16) __bf16 dlds[CHUNK][LROW];
  __shared__ float qscale[NQ];
  __shared__ float dscale[CHUNK];
  __shared__ float qkl[QK_SZ];

  const int b    = blockIdx.x >> 1;
  const int sp   = blockIdx.x & 1;
  const int t    = threadIdx.x;
  const int lane = t & 63;
  const int w    = t >> 6;

  // zero qkl for k>=1 (k==0 plain-stored by the match counter below)
  if (t < QK_SZ && (t % NK) != 0) qkl[t] = 0.0f;

  // ---- phase 1: query gather + norm scale + exact-match counts (kernel 0) ----
  {
    const int r = t >> 4;        // query row 0..31 (16 threads per row, same wave)
    const int j = t & 15;
    const int tq = qtok[b * NQ + r];
    const float4* rowp = (const float4*)(emb + (size_t)tq * NE);
    float ss = 0.0f;
    for (int c = j; c < NF4; c += 16) {
      float4 v = rowp[c];
      ss += v.x * v.x + v.y * v.y + v.z * v.z + v.w * v.w;
      bf16x4 h;
      h[0] = (__bf16)v.x; h[1] = (__bf16)v.y; h[2] = (__bf16)v.z; h[3] = (__bf16)v.w;
      *(bf16x4*)&qlds[r][4 * c] = h;
    }
    if (j < 5) {  // zero K-pad 300..319
      bf16x4 z = {};
      *(bf16x4*)&qlds[r][NE + 4 * j] = z;
    }
    ss += __shfl_xor(ss, 1, 16);
    ss += __shfl_xor(ss, 2, 16);
    ss += __shfl_xor(ss, 4, 16);
    ss += __shfl_xor(ss, 8, 16);
    if (j == 0) qscale[r] = (tq > 0) ? 1.0f / (sqrtf(ss) + 1e-13f) : 0.0f;

    // kernel 0: count of this block's DPB docs with identical (nonzero) token
    int cnt = 0;
    #pragma unroll
    for (int jj = 0; jj < DPB / 16; ++jj) {
      int td = dtok[b * ND + sp * DPB + j + 16 * jj];
      cnt += (tq > 0 && td == tq) ? 1 : 0;
    }
    cnt += __shfl_xor(cnt, 1, 16);
    cnt += __shfl_xor(cnt, 2, 16);
    cnt += __shfl_xor(cnt, 4, 16);
    cnt += __shfl_xor(cnt, 8, 16);
    if (j == 0) qkl[r * NK] = (float)cnt;
  }

  // ---- per-wave MFMA tile assignment ----
  const int mt  = w >> 2;      // m-tile 0/1 (q rows 16mt..16mt+15)
  const int nt  = w & 3;       // n-tile 0..3 (docs 16nt..16nt+15 within chunk)
  const int l15 = lane & 15;
  const int l4  = lane >> 4;

  float rbfacc[4][10];
  #pragma unroll
  for (int r4 = 0; r4 < 4; ++r4)
    #pragma unroll
    for (int k = 0; k < 10; ++k) rbfacc[r4][k] = 0.0f;

  const __bf16* aptr = &qlds[mt * 16 + l15][l4 * 8];
  const __bf16* bptr = &dlds[nt * 16 + l15][l4 * 8];

  const float muk[10] = {0.9f, 0.7f, 0.5f, 0.3f, 0.1f,
                         -0.1f, -0.3f, -0.5f, -0.7f, -0.9f};

  #pragma unroll 1
  for (int ch = 0; ch < NCHUNK; ++ch) {
    __syncthreads();  // prior MFMA reads of dlds done (and phase-1 writes visible)
    {
      const int r = t >> 3;    // doc row 0..63 (8 threads per row, same wave)
      const int j = t & 7;
      const int td = dtok[b * ND + sp * DPB + ch * CHUNK + r];
      const float4* rowp = (const float4*)(emb + (size_t)td * NE);
      float ss = 0.0f;
      for (int c = j; c < NF4; c += 8) {
        float4 v = rowp[c];
        ss += v.x * v.x + v.y * v.y + v.z * v.z + v.w * v.w;
        bf16x4 h;
        h[0] = (__bf16)v.x; h[1] = (__bf16)v.y; h[2] = (__bf16)v.z; h[3] = (__bf16)v.w;
        *(bf16x4*)&dlds[r][4 * c] = h;
      }
      if (j < 5) {  // zero K-pad 300..319
        bf16x4 z = {};
        *(bf16x4*)&dlds[r][NE + 4 * j] = z;
      }
      ss += __shfl_xor(ss, 1, 8);
      ss += __shfl_xor(ss, 2, 8);
      ss += __shfl_xor(ss, 4, 8);
      if (j == 0) dscale[r] = (td > 0) ? 1.0f / (sqrtf(ss) + 1e-13f) : 0.0f;
    }
    __syncthreads();

    // MFMA: mm tile (16x16) for this wave, K=320 in 10 steps
    f32x4 acc = {};
    #pragma unroll
    for (int k = 0; k < 10; ++k) {
      bf16x8 av = *(const bf16x8*)(aptr + k * 32);
      bf16x8 bv = *(const bf16x8*)(bptr + k * 32);
      acc = __builtin_amdgcn_mfma_f32_16x16x32_bf16(av, bv, acc, 0, 0, 0);
    }

    // RBF accumulate (kernels 1..10). C layout: col(doc)=l15, row(q)=l4*4+reg.
    const float ds = dscale[nt * 16 + l15];
    #pragma unroll
    for (int r4 = 0; r4 < 4; ++r4) {
      const float qs = qscale[mt * 16 + l4 * 4 + r4];
      const float s = qs * ds;
      const float mm = (s == 0.0f) ? 1e8f : acc[r4] * s;  // masked -> rbf underflows to 0
      #pragma unroll
      for (int k = 0; k < 10; ++k) {
        float d = mm - muk[k];
        rbfacc[r4][k] += __builtin_amdgcn_exp2f(d * d * -72.13475204444817f);
      }
    }
  }

  // ---- reduce rbfacc over the 16 doc-columns of this wave's tile, add into qkl ----
  #pragma unroll
  for (int r4 = 0; r4 < 4; ++r4)
    #pragma unroll
    for (int k = 0; k < 10; ++k) {
      float v = rbfacc[r4][k];
      v += __shfl_xor(v, 1);
      v += __shfl_xor(v, 2);
      v += __shfl_xor(v, 4);
      v += __shfl_xor(v, 8);
      if (l15 == 0) atomicAdd(&qkl[(mt * 16 + l4 * 4 + r4) * NK + k + 1], v);
    }
  __syncthreads();

  // ---- write this block's partial qk slice ----
  float* pp = partial + ((size_t)b * SPLITS + sp) * QK_SZ;
  for (int i = t; i < QK_SZ; i += NT) pp[i] = qkl[i];
}

__global__ __launch_bounds__(64) void knrm_epi(
    const float* __restrict__ partial,
    const float* __restrict__ fcw,
    const float* __restrict__ fcb,
    float* __restrict__ out)
{
  const int b = blockIdx.x;
  const int lane = threadIdx.x;
  const float* pb = partial + (size_t)b * SPLITS * QK_SZ;
  float acc = 0.0f;
  for (int i = lane; i < QK_SZ; i += 64) {
    float s = pb[i] + pb[i + QK_SZ];
    int k = i % NK;
    acc += logf(fmaxf(s, 1e-10f)) * 0.01f * fcw[k];
  }
  #pragma unroll
  for (int off = 1; off < 64; off <<= 1) acc += __shfl_xor(acc, off);
  if (lane == 0) out[b] = acc + fcb[0];
}

extern "C" void kernel_launch(void* const* d_in, const int* in_sizes, int n_in,
                              void* d_out, int out_size, void* d_ws, size_t ws_size,
                              hipStream_t stream) {
  const int* qtok = (const int*)d_in[0];
  const int* dtok = (const int*)d_in[1];
  const float* emb = (const float*)d_in[2];
  const float* fcw = (const float*)d_in[3];
  const float* fcb = (const float*)d_in[4];
  float* out = (float*)d_out;
  float* partial = (float*)d_ws;   // NB*SPLITS*QK_SZ floats = 720 KB

  knrm_main<<<NB * SPLITS, NT, 0, stream>>>(qtok, dtok, emb, partial);
  knrm_epi<<<NB, 64, 0, stream>>>(partial, fcw, fcb, out);
}

// Round 5
// 196.783 us; speedup vs baseline: 1.5300x; 1.0513x over previous
//
#include <hip/hip_runtime.h>
#include <hip/hip_bf16.h>
#include <math.h>

// KNRM fused kernel for MI355X (gfx950) — round 5.
// B=256, Q=32, D=512, E=300, V=100k, K=11.
//
// R5 = R4 + memory-level parallelism in the gathers: each thread preloads ALL
// its float4s for a row into a register array (9-10 independent loads in
// flight) before computing ss / converting / writing LDS. R4's fused loop kept
// only ~2 loads in flight at VGPR=52 -> ~35k cyc/chunk of serialized latency.
// __launch_bounds__(512,4) pins 16 waves/CU (the 2-blocks/CU that 63.5 KB LDS
// allows) with a 128-VGPR cap so the preload arrays don't spill.
// Kernel 0 (sigma=1e-4) = exact-token-match counter via integer compare.

#define NB 256
#define NQ 32
#define ND 512
#define NE 300
#define NF4 75      // float4 per emb row
#define LROW 328    // LDS row stride in bf16 (656 B = 16B-aligned, 4-bank row offset)
#define SPLITS 2
#define DPB 256     // docs per block
#define CHUNK 64
#define NCHUNK 4
#define NT 512
#define NK 11
#define QK_SZ (NQ * NK)   // 352

typedef __bf16 bf16x8 __attribute__((ext_vector_type(8)));
typedef __bf16 bf16x4 __attribute__((ext_vector_type(4)));
typedef float f32x4 __attribute__((ext_vector_type(4)));

__global__ __launch_bounds__(NT, 4) void knrm_main(
    const int* __restrict__ qtok,
    const int* __restrict__ dtok,
    const float* __restrict__ emb,
    float* __restrict__ partial)   // [NB][SPLITS][QK_SZ]
{
  __shared__ __align__(16) __bf16 qlds[NQ][LROW];
  __shared__ __align__(16) __bf16 dlds[CHUNK][LROW];
  __shared__ float qscale[NQ];
  __shared__ float dscale[CHUNK];
  __shared__ float qkl[QK_SZ];

  const int b    = blockIdx.x >> 1;
  const int sp   = blockIdx.x & 1;
  const int t    = threadIdx.x;
  const int lane = t & 63;
  const int w    = t >> 6;

  // zero qkl for k>=1 (k==0 plain-stored by the match counter below)
  if (t < QK_SZ && (t % NK) != 0) qkl[t] = 0.0f;

  // ---- phase 1: query gather + norm scale + exact-match counts (kernel 0) ----
  {
    const int r = t >> 4;        // query row 0..31 (16 threads per row, same wave)
    const int j = t & 15;
    const int tq = qtok[b * NQ + r];
    const float4* rowp = (const float4*)(emb + (size_t)tq * NE);

    // preload: all 4-5 float4s in flight before any use
    float4 v[5];
    #pragma unroll
    for (int i = 0; i < 4; ++i) v[i] = rowp[j + 16 * i];
    v[4] = (j < 11) ? rowp[j + 64] : make_float4(0.f, 0.f, 0.f, 0.f);

    float ss = 0.0f;
    #pragma unroll
    for (int i = 0; i < 5; ++i) {
      ss += v[i].x * v[i].x + v[i].y * v[i].y + v[i].z * v[i].z + v[i].w * v[i].w;
      if (i < 4 || j < 11) {
        bf16x4 h;
        h[0] = (__bf16)v[i].x; h[1] = (__bf16)v[i].y;
        h[2] = (__bf16)v[i].z; h[3] = (__bf16)v[i].w;
        *(bf16x4*)&qlds[r][4 * (j + 16 * i)] = h;
      }
    }
    if (j < 5) {  // zero K-pad 300..319
      bf16x4 z = {};
      *(bf16x4*)&qlds[r][NE + 4 * j] = z;
    }
    ss += __shfl_xor(ss, 1, 16);
    ss += __shfl_xor(ss, 2, 16);
    ss += __shfl_xor(ss, 4, 16);
    ss += __shfl_xor(ss, 8, 16);
    if (j == 0) qscale[r] = (tq > 0) ? 1.0f / (sqrtf(ss) + 1e-13f) : 0.0f;

    // kernel 0: count of this block's DPB docs with identical (nonzero) token
    int cnt = 0;
    #pragma unroll
    for (int jj = 0; jj < DPB / 16; ++jj) {
      int td = dtok[b * ND + sp * DPB + j + 16 * jj];
      cnt += (tq > 0 && td == tq) ? 1 : 0;
    }
    cnt += __shfl_xor(cnt, 1, 16);
    cnt += __shfl_xor(cnt, 2, 16);
    cnt += __shfl_xor(cnt, 4, 16);
    cnt += __shfl_xor(cnt, 8, 16);
    if (j == 0) qkl[r * NK] = (float)cnt;
  }

  // ---- per-wave MFMA tile assignment ----
  const int mt  = w >> 2;      // m-tile 0/1 (q rows 16mt..16mt+15)
  const int nt  = w & 3;       // n-tile 0..3 (docs 16nt..16nt+15 within chunk)
  const int l15 = lane & 15;
  const int l4  = lane >> 4;

  float rbfacc[4][10];
  #pragma unroll
  for (int r4 = 0; r4 < 4; ++r4)
    #pragma unroll
    for (int k = 0; k < 10; ++k) rbfacc[r4][k] = 0.0f;

  const __bf16* aptr = &qlds[mt * 16 + l15][l4 * 8];
  const __bf16* bptr = &dlds[nt * 16 + l15][l4 * 8];

  const float muk[10] = {0.9f, 0.7f, 0.5f, 0.3f, 0.1f,
                         -0.1f, -0.3f, -0.5f, -0.7f, -0.9f};

  #pragma unroll 1
  for (int ch = 0; ch < NCHUNK; ++ch) {
    __syncthreads();  // prior MFMA reads of dlds done (and phase-1 writes visible)
    {
      const int r = t >> 3;    // doc row 0..63 (8 threads per row, same wave)
      const int j = t & 7;
      const int td = dtok[b * ND + sp * DPB + ch * CHUNK + r];
      const float4* rowp = (const float4*)(emb + (size_t)td * NE);

      // preload: all 9-10 float4s in flight before any use
      float4 v[10];
      #pragma unroll
      for (int i = 0; i < 9; ++i) v[i] = rowp[j + 8 * i];
      v[9] = (j < 3) ? rowp[j + 72] : make_float4(0.f, 0.f, 0.f, 0.f);

      float ss = 0.0f;
      #pragma unroll
      for (int i = 0; i < 10; ++i) {
        ss += v[i].x * v[i].x + v[i].y * v[i].y + v[i].z * v[i].z + v[i].w * v[i].w;
        if (i < 9 || j < 3) {
          bf16x4 h;
          h[0] = (__bf16)v[i].x; h[1] = (__bf16)v[i].y;
          h[2] = (__bf16)v[i].z; h[3] = (__bf16)v[i].w;
          *(bf16x4*)&dlds[r][4 * (j + 8 * i)] = h;
        }
      }
      if (j < 5) {  // zero K-pad 300..319
        bf16x4 z = {};
        *(bf16x4*)&dlds[r][NE + 4 * j] = z;
      }
      ss += __shfl_xor(ss, 1, 8);
      ss += __shfl_xor(ss, 2, 8);
      ss += __shfl_xor(ss, 4, 8);
      if (j == 0) dscale[r] = (td > 0) ? 1.0f / (sqrtf(ss) + 1e-13f) : 0.0f;
    }
    __syncthreads();

    // MFMA: mm tile (16x16) for this wave, K=320 in 10 steps
    f32x4 acc = {};
    #pragma unroll
    for (int k = 0; k < 10; ++k) {
      bf16x8 av = *(const bf16x8*)(aptr + k * 32);
      bf16x8 bv = *(const bf16x8*)(bptr + k * 32);
      acc = __builtin_amdgcn_mfma_f32_16x16x32_bf16(av, bv, acc, 0, 0, 0);
    }

    // RBF accumulate (kernels 1..10). C layout: col(doc)=l15, row(q)=l4*4+reg.
    const float ds = dscale[nt * 16 + l15];
    #pragma unroll
    for (int r4 = 0; r4 < 4; ++r4) {
      const float qs = qscale[mt * 16 + l4 * 4 + r4];
      const float s = qs * ds;
      const float mm = (s == 0.0f) ? 1e8f : acc[r4] * s;  // masked -> rbf underflows to 0
      #pragma unroll
      for (int k = 0; k < 10; ++k) {
        float d = mm - muk[k];
        rbfacc[r4][k] += __builtin_amdgcn_exp2f(d * d * -72.13475204444817f);
      }
    }
  }

  // ---- reduce rbfacc over the 16 doc-columns of this wave's tile, add into qkl ----
  #pragma unroll
  for (int r4 = 0; r4 < 4; ++r4)
    #pragma unroll
    for (int k = 0; k < 10; ++k) {
      float v = rbfacc[r4][k];
      v += __shfl_xor(v, 1);
      v += __shfl_xor(v, 2);
      v += __shfl_xor(v, 4);
      v += __shfl_xor(v, 8);
      if (l15 == 0) atomicAdd(&qkl[(mt * 16 + l4 * 4 + r4) * NK + k + 1], v);
    }
  __syncthreads();

  // ---- write this block's partial qk slice ----
  float* pp = partial + ((size_t)b * SPLITS + sp) * QK_SZ;
  for (int i = t; i < QK_SZ; i += NT) pp[i] = qkl[i];
}

__global__ __launch_bounds__(64) void knrm_epi(
    const float* __restrict__ partial,
    const float* __restrict__ fcw,
    const float* __restrict__ fcb,
    float* __restrict__ out)
{
  const int b = blockIdx.x;
  const int lane = threadIdx.x;
  const float* pb = partial + (size_t)b * SPLITS * QK_SZ;
  float acc = 0.0f;
  for (int i = lane; i < QK_SZ; i += 64) {
    float s = pb[i] + pb[i + QK_SZ];
    int k = i % NK;
    acc += logf(fmaxf(s, 1e-10f)) * 0.01f * fcw[k];
  }
  #pragma unroll
  for (int off = 1; off < 64; off <<= 1) acc += __shfl_xor(acc, off);
  if (lane == 0) out[b] = acc + fcb[0];
}

extern "C" void kernel_launch(void* const* d_in, const int* in_sizes, int n_in,
                              void* d_out, int out_size, void* d_ws, size_t ws_size,
                              hipStream_t stream) {
  const int* qtok = (const int*)d_in[0];
  const int* dtok = (const int*)d_in[1];
  const float* emb = (const float*)d_in[2];
  const float* fcw = (const float*)d_in[3];
  const float* fcb = (const float*)d_in[4];
  float* out = (float*)d_out;
  float* partial = (float*)d_ws;   // NB*SPLITS*QK_SZ floats = 720 KB

  knrm_main<<<NB * SPLITS, NT, 0, stream>>>(qtok, dtok, emb, partial);
  knrm_epi<<<NB, 64, 0, stream>>>(partial, fcw, fcb, out);
}